// Round 2
// baseline (320.103 us; speedup 1.0000x reference)
//
#include <hip/hip_runtime.h>
#include <stdint.h>

#define THR  1.0f
#define BETA 0.95f

typedef __attribute__((ext_vector_type(8)))  short  bf16x8;
typedef __attribute__((ext_vector_type(16))) float  f32x16;
typedef __attribute__((ext_vector_type(4)))  float  fvec4;

// Exact 3-way truncated bf16 split: w == wh + wm + wl exactly (24 = 3x8 mantissa bits).
__global__ void split_w1(const float* __restrict__ W1,
                         unsigned short* __restrict__ wh,
                         unsigned short* __restrict__ wm,
                         unsigned short* __restrict__ wl){
  int i = blockIdx.x * 256 + threadIdx.x;
  if (i < 128 * 784) {
    float v = W1[i];
    uint32_t u  = __float_as_uint(v);
    uint32_t uh = u & 0xFFFF0000u;
    float vm = v - __uint_as_float(uh);
    uint32_t um = __float_as_uint(vm) & 0xFFFF0000u;
    float vl = vm - __uint_as_float(um);          // exactly representable in bf16
    wh[i] = (unsigned short)(uh >> 16);
    wm[i] = (unsigned short)(um >> 16);
    wl[i] = (unsigned short)(__float_as_uint(vl) >> 16);
  }
}

// cur1[m][h] = sum_k x[row0+m][k] * W1[h][k]   (bias added later in lif)
// Each wave computes a 64(M) x 128(N) strip. No LDS.
// 6-term exact-split MFMA: hh + hm + mh + mm + hl + lh (drops only <=2^-24 rel terms).
__launch_bounds__(256, 2)
__global__ void gemm1(const float* __restrict__ x,
                      const unsigned short* __restrict__ wh,
                      const unsigned short* __restrict__ wm,
                      const unsigned short* __restrict__ wl,
                      float* __restrict__ cur1,
                      long row0){
  const int lane = threadIdx.x & 63;
  const int wid  = threadIdx.x >> 6;
  const long m0  = (long)blockIdx.x * 256 + (long)wid * 64;
  const int r  = lane & 31;   // row (A) / col (B) within 32-frag
  const int kg = lane >> 5;   // k-group: 8 contiguous k per lane

  const float* xr0 = x + (row0 + m0 + r) * 784 + kg * 8;
  const float* xr1 = xr0 + 32 * 784;
  const int wbase[4] = { (0 * 32 + r) * 784 + kg * 8,
                         (1 * 32 + r) * 784 + kg * 8,
                         (2 * 32 + r) * 784 + kg * 8,
                         (3 * 32 + r) * 784 + kg * 8 };

  f32x16 acc[2][4] = {};

  for (int k0 = 0; k0 < 784; k0 += 16) {
    bf16x8 bh[4], bm[4], bl[4];
    #pragma unroll
    for (int nf = 0; nf < 4; ++nf) {
      bh[nf] = *(const bf16x8*)(wh + wbase[nf] + k0);
      bm[nf] = *(const bf16x8*)(wm + wbase[nf] + k0);
      bl[nf] = *(const bf16x8*)(wl + wbase[nf] + k0);
    }
    bf16x8 ah[2], am[2], al[2];
    #pragma unroll
    for (int mf = 0; mf < 2; ++mf) {
      const float* p = (mf == 0 ? xr0 : xr1) + k0;
      fvec4 a0 = *(const fvec4*)(p);
      fvec4 a1 = *(const fvec4*)(p + 4);
      bf16x8 h, m, l;
      #pragma unroll
      for (int j = 0; j < 8; ++j) {
        float v = (j < 4) ? a0[j] : a1[j - 4];
        uint32_t u  = __float_as_uint(v);
        uint32_t uh = u & 0xFFFF0000u;
        float vm = v - __uint_as_float(uh);
        uint32_t um = __float_as_uint(vm) & 0xFFFF0000u;
        float vl = vm - __uint_as_float(um);
        h[j] = (short)(uh >> 16);
        m[j] = (short)(um >> 16);
        l[j] = (short)(__float_as_uint(vl) >> 16);
      }
      ah[mf] = h; am[mf] = m; al[mf] = l;
    }
    #pragma unroll
    for (int mf = 0; mf < 2; ++mf) {
      #pragma unroll
      for (int nf = 0; nf < 4; ++nf) {
        acc[mf][nf] = __builtin_amdgcn_mfma_f32_32x32x16_bf16(ah[mf], bh[nf], acc[mf][nf], 0, 0, 0);
        acc[mf][nf] = __builtin_amdgcn_mfma_f32_32x32x16_bf16(ah[mf], bm[nf], acc[mf][nf], 0, 0, 0);
        acc[mf][nf] = __builtin_amdgcn_mfma_f32_32x32x16_bf16(am[mf], bh[nf], acc[mf][nf], 0, 0, 0);
        acc[mf][nf] = __builtin_amdgcn_mfma_f32_32x32x16_bf16(am[mf], bm[nf], acc[mf][nf], 0, 0, 0);
        acc[mf][nf] = __builtin_amdgcn_mfma_f32_32x32x16_bf16(ah[mf], bl[nf], acc[mf][nf], 0, 0, 0);
        acc[mf][nf] = __builtin_amdgcn_mfma_f32_32x32x16_bf16(al[mf], bh[nf], acc[mf][nf], 0, 0, 0);
      }
    }
  }

  // C/D layout (m74/m101-verified): col = lane&31, row = (reg&3) + 8*(reg>>2) + 4*(lane>>5)
  #pragma unroll
  for (int mf = 0; mf < 2; ++mf)
    #pragma unroll
    for (int nf = 0; nf < 4; ++nf)
      #pragma unroll
      for (int reg = 0; reg < 16; ++reg) {
        int row = (reg & 3) + 8 * (reg >> 2) + 4 * kg;
        long m = m0 + mf * 32 + row;
        cur1[m * 128 + nf * 32 + r] = acc[mf][nf][reg];
      }
}

// LIF recurrence + layer 2. One wave per batch element b; lane owns h=lane, h=lane+64.
// Layer-2 reduction via ballot bitmask + per-lane 32-bit chunk weight sums.
__launch_bounds__(256)
__global__ void lif(const float* __restrict__ cur1,
                    const float* __restrict__ b1,
                    const float* __restrict__ W2,
                    const float* __restrict__ b2,
                    float* __restrict__ out,
                    float* __restrict__ state1,
                    float* __restrict__ state2,
                    int t0, int tn){
  const int lane = threadIdx.x & 63;
  const int b = blockIdx.x * 4 + (threadIdx.x >> 6);
  const int o = lane & 15;    // output index this lane accumulates (valid if <10)
  const int c = lane >> 4;    // h-chunk 0..3 (32 h each)

  float wv[32];
  #pragma unroll
  for (int j = 0; j < 32; ++j) wv[j] = 0.f;
  if (o < 10) {
    #pragma unroll
    for (int j = 0; j < 32; ++j) wv[j] = W2[o * 128 + c * 32 + j];
  }
  float b1a = b1[lane], b1b = b1[64 + lane];
  float b2v = (lane < 10) ? b2[lane] : 0.f;

  float mem1a, mem1b, mem2;
  if (t0 == 0) { mem1a = 0.f; mem1b = 0.f; mem2 = 0.f; }
  else {
    mem1a = state1[b * 128 + lane];
    mem1b = state1[b * 128 + 64 + lane];
    mem2  = (lane < 10) ? state2[b * 10 + lane] : 0.f;
  }

  for (int t = t0; t < tn; ++t) {
    long base = ((long)(t - t0) * 4096 + b) * 128;
    float c1a = cur1[base + lane] + b1a;
    float c1b = cur1[base + 64 + lane] + b1b;
    float r1a = (mem1a > THR) ? THR : 0.f;   // reset uses OLD mem
    float r1b = (mem1b > THR) ? THR : 0.f;
    mem1a = BETA * mem1a + c1a - r1a;
    mem1b = BETA * mem1b + c1b - r1b;

    uint64_t mA = __ballot(mem1a > THR);  // spk1 bits for h = lane
    uint64_t mB = __ballot(mem1b > THR);  // spk1 bits for h = 64 + lane
    uint64_t m64 = (c & 2) ? mB : mA;
    uint32_t bits = (uint32_t)(m64 >> ((c & 1) << 5));

    float s = 0.f;
    #pragma unroll
    for (int j = 0; j < 32; ++j) {
      int msk = (int)(bits << (31 - j)) >> 31;           // -(bit j)
      s += __int_as_float(msk & __float_as_int(wv[j]));  // + wv[j] or +0
    }
    // combine the 4 chunks (lanes l, l^16, l^32, l^48 share o)
    s += __shfl_xor(s, 16);
    s += __shfl_xor(s, 32);

    if (lane < 10) {
      float cur2 = s + b2v;
      float r2 = (mem2 > THR) ? THR : 0.f;
      mem2 = BETA * mem2 + cur2 - r2;
      float s2 = (mem2 > THR) ? 1.f : 0.f;
      long ob = (long)t * 40960 + (long)b * 10 + lane;
      out[ob] = s2;
      out[1228800 + ob] = mem2;
    }
  }

  if (tn < 30) {
    state1[b * 128 + lane] = mem1a;
    state1[b * 128 + 64 + lane] = mem1b;
    if (lane < 10) state2[b * 10 + lane] = mem2;
  }
}

extern "C" void kernel_launch(void* const* d_in, const int* in_sizes, int n_in,
                              void* d_out, int out_size, void* d_ws, size_t ws_size,
                              hipStream_t stream) {
  const float* x  = (const float*)d_in[0];
  const float* W1 = (const float*)d_in[1];
  const float* b1 = (const float*)d_in[2];
  const float* W2 = (const float*)d_in[3];
  const float* b2 = (const float*)d_in[4];
  float* out = (float*)d_out;

  const int T = 30, B = 4096;
  const int W1N = 128 * 784;

  char* ws = (char*)d_ws;
  unsigned short* wh = (unsigned short*)ws;
  unsigned short* wm = wh + W1N;
  unsigned short* wl = wm + W1N;
  size_t off = (size_t)3 * W1N * sizeof(unsigned short);
  off = (off + 255) & ~(size_t)255;
  float* state1 = (float*)(ws + off); off += (size_t)B * 128 * 4;
  float* state2 = (float*)(ws + off); off += (size_t)B * 10 * 4;
  off = (off + 255) & ~(size_t)255;
  float* cur1 = (float*)(ws + off);

  size_t per_t = (size_t)B * 128 * 4;
  size_t avail = (ws_size > off) ? (ws_size - off) : 0;
  int CH = (int)(avail / per_t);
  if (CH > T) CH = T;
  if (CH < 1) CH = 1;

  split_w1<<<(W1N + 255) / 256, 256, 0, stream>>>(W1, wh, wm, wl);

  for (int t0 = 0; t0 < T; t0 += CH) {
    int tn = (t0 + CH < T) ? (t0 + CH) : T;
    int mrows = (tn - t0) * B;                   // multiple of 4096 -> multiple of 256
    gemm1<<<mrows / 256, 256, 0, stream>>>(x, wh, wm, wl, cur1, (long)t0 * B);
    lif<<<B / 4, 256, 0, stream>>>(cur1, b1, W2, b2, out, state1, state2, t0, tn);
  }
}